// Round 15
// baseline (1920.780 us; speedup 1.0000x reference)
//
#include <hip/hip_runtime.h>
#include <hip/hip_bf16.h>
#include <cmath>

// ---- constants -------------------------------------------------------------
#define Bsz   4
#define Tlen  2048
#define Cdim  2048
#define Hn    16
#define Dh    128
#define N_QKV 6144
#define Mrows 8192          // B*T

typedef __bf16 bf16x8 __attribute__((ext_vector_type(8)));
typedef __bf16 bf16x4 __attribute__((ext_vector_type(4)));
typedef float  f32x4  __attribute__((ext_vector_type(4)));
typedef uint32_t u32x2 __attribute__((ext_vector_type(2)));

__device__ __forceinline__ f32x4 mfma16(bf16x8 a, bf16x8 b, f32x4 c) {
  return __builtin_amdgcn_mfma_f32_16x16x32_bf16(a, b, c, 0, 0, 0);
}

__device__ __forceinline__ void gl16(const void* g, void* l) {
  __builtin_amdgcn_global_load_lds(
      (const __attribute__((address_space(1))) void*)g,
      (__attribute__((address_space(3))) void*)l, 16, 0, 0);
}

__device__ __forceinline__ uint32_t pack_bf16(float lo, float hi) {
  union { __bf16 h; unsigned short u; } a, b;
  a.h = (__bf16)lo; b.h = (__bf16)hi;
  return (uint32_t)a.u | ((uint32_t)b.u << 16);
}

// ---- 0) RoPE cos/sin table: [T][64] each ----------------------------------
__global__ void rope_table_k(float* __restrict__ cosT, float* __restrict__ sinT) {
  int idx = blockIdx.x * 256 + threadIdx.x;
  int t = idx >> 6, i = idx & 63;
  float invf = __expf(-(float)i * 0.14391156698f);   // 10000^(-i/64)
  float a = (float)t * invf;
  float s, c;
  sincosf(a, &s, &c);
  cosT[idx] = c;
  sinT[idx] = s;
}

// ---- 0b) X fp32 -> bf16 (row-major) ----------------------------------------
__global__ __launch_bounds__(256) void f32_to_bf16_k(
    const float* __restrict__ src, __bf16* __restrict__ dst) {
  size_t i = ((size_t)blockIdx.x * 256 + threadIdx.x) * 8;
  f32x4 a = *(const f32x4*)(src + i);
  f32x4 b = *(const f32x4*)(src + i + 4);
  bf16x8 o;
  o[0] = (__bf16)a[0]; o[1] = (__bf16)a[1]; o[2] = (__bf16)a[2]; o[3] = (__bf16)a[3];
  o[4] = (__bf16)b[0]; o[5] = (__bf16)b[1]; o[6] = (__bf16)b[2]; o[7] = (__bf16)b[3];
  *(bf16x8*)(dst + i) = o;
}

// ---- 0c) W fp32 [K][N] -> bf16 [N][K] (B^T form) ---------------------------
__global__ __launch_bounds__(256) void transpose_to_bf16_k(
    const float* __restrict__ src, __bf16* __restrict__ dst, int K, int N) {
  __shared__ float tile[32][33];
  int n0 = blockIdx.x * 32, k0 = blockIdx.y * 32;
  int tr = threadIdx.x >> 3, tc = (threadIdx.x & 7) * 4;
  f32x4 v = *(const f32x4*)&src[(size_t)(k0 + tr) * N + n0 + tc];
  tile[tr][tc + 0] = v[0]; tile[tr][tc + 1] = v[1];
  tile[tr][tc + 2] = v[2]; tile[tr][tc + 3] = v[3];
  __syncthreads();
  bf16x4 w;
  w[0] = (__bf16)tile[tc + 0][tr];
  w[1] = (__bf16)tile[tc + 1][tr];
  w[2] = (__bf16)tile[tc + 2][tr];
  w[3] = (__bf16)tile[tc + 3][tr];
  *(bf16x4*)&dst[(size_t)(n0 + tr) * K + k0 + tc] = w;
}

// ---- 1) QKV GEMM: 256x256, 8 waves, BK=32, dbuf, 2 blocks/CU ---------------
// Xb [8192][2048] bf16, Wt [6144][2048] bf16 (B^T).
// Q,K RoPE'd -> [B][H][T][D]; V -> TRANSPOSED [B][H][D][T].
__global__ __launch_bounds__(512, 4) void qkv_gemm(
    const __bf16* __restrict__ Xb, const __bf16* __restrict__ Wt,
    __bf16* __restrict__ Qo, __bf16* __restrict__ Ko, __bf16* __restrict__ Vo,
    const float* __restrict__ cosT, const float* __restrict__ sinT)
{
  __shared__ union SM {
    struct { __bf16 A[2][256 * 32]; __bf16 B[2][256 * 32]; } s;  // 64 KB dbuf
    float C[64][265];                                            // epilogue
  } sm;

  const int tid = threadIdx.x, lane = tid & 63, wid = tid >> 6;
  const int g = lane >> 4, l16 = lane & 15;
  const int wr = wid >> 2, wc = wid & 3;       // 2 x 4 wave grid
  const int sr0 = lane >> 2;                   // staging row-in-16

  // supertile: 768 blocks = 8 xcd * 6 stl * 16 pos; each XCD owns 4 by-rows
  const int bid = blockIdx.x;
  const int xcd = bid & 7, idx = bid >> 3;
  const int stl = idx >> 4, pos = idx & 15;
  const int m0 = (xcd * 4 + (pos >> 2)) * 256;
  const int n0 = (stl * 4 + (pos & 3)) * 256;

  f32x4 acc[8][4] = {};
  const int NT = Cdim / 32;   // 64 K-tiles

  // stage tile t_ into buffer buf_: 4 gl16/thread (2 A + 2 B)
#define QSTAGE(buf_, t_) {                                                    \
    _Pragma("unroll") for (int j = 0; j < 2; ++j) {                           \
      const int rr = wid * 32 + j * 16 + sr0;                                 \
      const int sc = (lane & 3) ^ ((rr >> 1) & 3);                            \
      gl16(Xb + (size_t)(m0 + rr) * Cdim + (t_) * 32 + sc * 8,                \
           &sm.s.A[buf_][(wid * 32 + j * 16) * 32]);                          \
      gl16(Wt + (size_t)(n0 + rr) * Cdim + (t_) * 32 + sc * 8,                \
           &sm.s.B[buf_][(wid * 32 + j * 16) * 32]);                          \
    } }

  QSTAGE(0, 0)
  QSTAGE(1, 1)

  for (int t = 0; t < NT; ++t) {
    const int p = t & 1;
    if (t < NT - 1) asm volatile("s_waitcnt vmcnt(4)" ::: "memory");
    else            asm volatile("s_waitcnt vmcnt(0)" ::: "memory");
    __builtin_amdgcn_s_barrier();
    __builtin_amdgcn_sched_barrier(0);

    {
      bf16x8 a[8], b[4];
      const int ch = (g ^ ((l16 >> 1) & 3)) * 8;
      #pragma unroll
      for (int f = 0; f < 8; ++f)
        a[f] = *(const bf16x8*)&sm.s.A[p][(wr * 128 + f * 16 + l16) * 32 + ch];
      #pragma unroll
      for (int n = 0; n < 4; ++n)
        b[n] = *(const bf16x8*)&sm.s.B[p][(wc * 64 + n * 16 + l16) * 32 + ch];
      #pragma unroll
      for (int f = 0; f < 8; ++f)
        #pragma unroll
        for (int n = 0; n < 4; ++n)
          acc[f][n] = mfma16(a[f], b[n], acc[f][n]);
    }

    __builtin_amdgcn_sched_barrier(0);
    asm volatile("s_waitcnt lgkmcnt(0)" ::: "memory");
    __builtin_amdgcn_s_barrier();

    if (t + 2 < NT) QSTAGE(p, t + 2)
  }
#undef QSTAGE

  // epilogue: four 64-row rounds through LDS f32
  const int sel = n0 >> 11;             // 0=q 1=k 2=v
  const int h0  = (n0 & 2047) >> 7;     // first of 2 heads in this tile
  const int erow = tid >> 3, q = tid & 7;
  const int dlo = (q & 3) * 16;
  const int clo = (q >> 2) * 128 + dlo;
  const int vcol = tid >> 1, vth = tid & 1;      // V^T path mapping

  #pragma unroll
  for (int rh = 0; rh < 4; ++rh) {
    if (wr == (rh >> 1)) {
      const int fb = (rh & 1) * 4;
      #pragma unroll
      for (int f2 = 0; f2 < 4; ++f2)
        #pragma unroll
        for (int n = 0; n < 4; ++n)
          #pragma unroll
          for (int r = 0; r < 4; ++r)
            sm.C[f2 * 16 + g * 4 + r][wc * 64 + n * 16 + l16] = acc[fb + f2][n][r];
    }
    __syncthreads();
    if (sel == 2) {
      // V^T write: thread owns (head', d) column, writes 32 t-contiguous vals
      const int hh = h0 + (vcol >> 7), d = vcol & 127;
      const int mb = m0 + rh * 64 + vth * 32;
      const int b_ = mb >> 11, tt = mb & 2047;
      __bf16* outp = Vo + (((size_t)(b_ * Hn + hh)) * Dh + d) * Tlen + tt;
      bf16x8 w[4];
      #pragma unroll
      for (int i = 0; i < 32; ++i)
        w[i >> 3][i & 7] = (__bf16)sm.C[vth * 32 + i][vcol];
      #pragma unroll
      for (int k = 0; k < 4; ++k) *(bf16x8*)&outp[k * 8] = w[k];
    } else {
      __bf16* dst = (sel == 0) ? Qo : Ko;
      const int m = m0 + rh * 64 + erow;
      const int b_ = m >> 11, t = m & 2047;
      __bf16* out = dst + (((size_t)(b_ * Hn + h0 + (q >> 2))) * Tlen + t) * Dh + dlo;
      const float* cb = cosT + t * 64 + dlo;
      const float* sb = sinT + t * 64 + dlo;
      bf16x8 o1[2], o2[2];
      #pragma unroll
      for (int i = 0; i < 16; ++i) {
        float v1 = sm.C[erow][clo + i];
        float v2 = sm.C[erow][clo + i + 64];
        float cs = cb[i], sn = sb[i];
        float r1 = v1 * cs - v2 * sn;
        float r2 = v2 * cs + v1 * sn;
        o1[i >> 3][i & 7] = (__bf16)r1;
        o2[i >> 3][i & 7] = (__bf16)r2;
      }
      *(bf16x8*)&out[0]  = o1[0];
      *(bf16x8*)&out[8]  = o1[1];
      *(bf16x8*)&out[64] = o2[0];
      *(bf16x8*)&out[72] = o2[1];
    }
    __syncthreads();
  }
}

// ---- 2) Flash attention (causal), swapped QK^T, in-register softmax --------
// Q,K bf16 [B][H][T][D]; V bf16 [B][H][D][T] (pre-transposed); Y -> [B][T][C].
__global__ __launch_bounds__(256, 2) void attn_fwd(
    const __bf16* __restrict__ Qg, const __bf16* __restrict__ Kg,
    const __bf16* __restrict__ Vtg, __bf16* __restrict__ Yg)
{
  __shared__ __bf16 Ks[2][64 * 128];       // XOR-chunk swizzled
  __shared__ __bf16 Vt[2][128 * 64];       // V^T tile, swizzled
  __shared__ uint32_t Ps2[4][16 * 34 + 2]; // per-wave P in B-frag layout (u32 pairs)

  const int tid = threadIdx.x, lane = tid & 63, wid = tid >> 6;
  const int g = lane >> 4, l16 = lane & 15;
  const int qt = gridDim.x - 1 - blockIdx.x;     // heavy blocks first
  const int q0 = qt * 64;
  const size_t bh = (size_t)blockIdx.z * Hn + blockIdx.y;
  const __bf16* Kbase = Kg + bh * ((size_t)Tlen * Dh);
  const __bf16* Vbase = Vtg + bh * ((size_t)Dh * Tlen);

  const int q_glob = q0 + wid * 16 + l16;        // this lane's q row

  // Q fragments in registers: B-operand, B[k=8g+j][col=q=l16]
  bf16x8 aq[4];
  {
    const __bf16* qrow = Qg + (bh * Tlen + q_glob) * Dh;
    #pragma unroll
    for (int ks = 0; ks < 4; ++ks)
      aq[ks] = *(const bf16x8*)(qrow + ks * 32 + 8 * g);
  }

  float m_r = -1e30f, l_r = 0.f;
  f32x4 o[8] = {};                               // O^T: d = 16n2+4g+r, q = l16
  const float k_e = 0.08838834764831845f * 1.4426950408889634f; // scl*log2(e)

  const int NKV = qt + 1;

  const int krow = lane >> 4, kchk = lane & 15;
  const int vrow = lane >> 3, vchk = lane & 7;

#define STAGE_KV(kv0_, buf_)                                                    \
  {                                                                             \
    _Pragma("unroll")                                                           \
    for (int rr = 0; rr < 4; ++rr) {                                            \
      const int row = wid * 16 + rr * 4 + krow;                                 \
      const int sc = kchk ^ (row & 7);                                          \
      gl16(Kbase + (size_t)((kv0_) + row) * Dh + sc * 8,                        \
           &Ks[buf_][(wid * 16 + rr * 4) * 128]);                               \
    }                                                                           \
    _Pragma("unroll")                                                           \
    for (int rr = 0; rr < 4; ++rr) {                                            \
      const int row = wid * 32 + rr * 8 + vrow;                                 \
      const int sc = vchk ^ (row & 7);                                          \
      gl16(Vbase + (size_t)row * Tlen + (kv0_) + sc * 8,                        \
           &Vt[buf_][(wid * 32 + rr * 8) * 64]);                                \
    }                                                                           \
  }

  STAGE_KV(0, 0);

  for (int it = 0; it < NKV; ++it) {
    const int p = it & 1;
    if (it + 1 < NKV) {
      STAGE_KV((it + 1) * 64, (it + 1) & 1);
      asm volatile("s_waitcnt vmcnt(8)" ::: "memory");
    } else {
      asm volatile("s_waitcnt vmcnt(0)" ::: "memory");
    }
    __builtin_amdgcn_s_barrier();
    __builtin_amdgcn_sched_barrier(0);

    // S^T = K Q^T : s[nf][r] = S[kv = it*64 + nf*16 + 4g + r][q = l16]
    f32x4 s[4] = {};
    __builtin_amdgcn_s_setprio(1);
    #pragma unroll
    for (int ks = 0; ks < 4; ++ks) {
      const int ch = ((4 * ks + g) ^ (l16 & 7)) * 8;
      #pragma unroll
      for (int nf = 0; nf < 4; ++nf) {
        bf16x8 bk = *(const bf16x8*)&Ks[p][(nf * 16 + l16) * 128 + ch];
        s[nf] = mfma16(bk, aq[ks], s[nf]);     // swapped: A=K, B=Q^T
      }
    }
    __builtin_amdgcn_s_setprio(0);

    if (it == qt) {                              // diagonal tile: causal mask
      const int kvb = it * 64 + 4 * g;
      #pragma unroll
      for (int nf = 0; nf < 4; ++nf)
        #pragma unroll
        for (int r = 0; r < 4; ++r)
          if (kvb + nf * 16 + r > q_glob) s[nf][r] = -1e30f;
    }

    // per-lane max over 16 kv values + 2-stage cross-g reduce
    float mx = s[0][0];
    #pragma unroll
    for (int nf = 0; nf < 4; ++nf)
      #pragma unroll
      for (int r = 0; r < 4; ++r) mx = fmaxf(mx, s[nf][r]);
    mx = fmaxf(mx, __shfl_xor(mx, 16, 64));
    mx = fmaxf(mx, __shfl_xor(mx, 32, 64));

    // T13 defer-max: only rescale when max grew by more than THR=8.
    if (!__all(mx - m_r <= 8.0f)) {
      const float mn = fmaxf(m_r, mx);
      const float al = exp2f((m_r - mn) * k_e);
      m_r = mn;
      l_r *= al;
      #pragma unroll
      for (int n2 = 0; n2 < 8; ++n2)
        #pragma unroll
        for (int r = 0; r < 4; ++r) o[n2][r] *= al;
    }

    const float mk = -m_r * k_e;
    float rs = 0.f;
    #pragma unroll
    for (int nf = 0; nf < 4; ++nf)
      #pragma unroll
      for (int r = 0; r < 4; ++r) {
        const float pv = exp2f(fmaf(s[nf][r], k_e, mk));
        s[nf][r] = pv;
        rs += pv;
      }
    rs += __shfl_xor(rs, 16, 64);
    rs += __shfl_xor(rs, 32, 64);
    l_r += rs;

    // P -> B-fragment layout via per-wave LDS: row q=l16, u32 col = kv/2
    #pragma unroll
    for (int nf = 0; nf < 4; ++nf) {
      u32x2 wv;
      wv.x = pack_bf16(s[nf][0], s[nf][1]);
      wv.y = pack_bf16(s[nf][2], s[nf][3]);
      *(u32x2*)&Ps2[wid][l16 * 34 + nf * 8 + 2 * g] = wv;   // kv = 16nf+4g+0..3
    }
    asm volatile("s_waitcnt lgkmcnt(0)" ::: "memory");
    __builtin_amdgcn_sched_barrier(0);

    union { u32x2 h[2]; bf16x8 v; } pb0, pb1;
    pb0.h[0] = *(const u32x2*)&Ps2[wid][l16 * 34 + 4 * g];
    pb0.h[1] = *(const u32x2*)&Ps2[wid][l16 * 34 + 4 * g + 2];
    pb1.h[0] = *(const u32x2*)&Ps2[wid][l16 * 34 + 16 + 4 * g];
    pb1.h[1] = *(const u32x2*)&Ps2[wid][l16 * 34 + 16 + 4 * g + 2];

    const int c0 = (g ^ (l16 & 7)) * 8;
    const int c1 = ((4 + g) ^ (l16 & 7)) * 8;
    __builtin_amdgcn_s_setprio(1);
    #pragma unroll
    for (int n2 = 0; n2 < 8; ++n2) {
      bf16x8 vb0 = *(const bf16x8*)&Vt[p][(n2 * 16 + l16) * 64 + c0];
      bf16x8 vb1 = *(const bf16x8*)&Vt[p][(n2 * 16 + l16) * 64 + c1];
      o[n2] = mfma16(vb0, pb0.v, o[n2]);         // O^T = V^T P
      o[n2] = mfma16(vb1, pb1.v, o[n2]);
    }
    __builtin_amdgcn_s_setprio(0);

    asm volatile("s_waitcnt lgkmcnt(0)" ::: "memory");
    __builtin_amdgcn_sched_barrier(0);
    __builtin_amdgcn_s_barrier();
  }
#undef STAGE_KV

  const float inv = 1.0f / l_r;
  // lane writes q-row q_glob, d = 16n2 + 4g + r (bf16x4 8B stores)
  __bf16* yrow = Yg + ((size_t)(blockIdx.z * Tlen + q0 + wid * 16 + l16)) * Cdim
               + blockIdx.y * Dh;
  #pragma unroll
  for (int n2 = 0; n2 < 8; ++n2) {
    bf16x4 w;
    #pragma unroll
    for (int r = 0; r < 4; ++r) w[r] = (__bf16)(o[n2][r] * inv);
    *(bf16x4*)&yrow[n2 * 16 + 4 * g] = w;
  }
}

// ---- 3) output GEMM: 256x256, 8 waves, BK=32, dbuf, 2 blocks/CU ------------
__global__ __launch_bounds__(512, 4) void out_gemm(
    const __bf16* __restrict__ Yb, const __bf16* __restrict__ Wt,
    float* __restrict__ O)
{
  __shared__ struct { __bf16 A[2][256 * 32]; __bf16 B[2][256 * 32]; } sm;

  const int tid = threadIdx.x, lane = tid & 63, wid = tid >> 6;
  const int g = lane >> 4, l16 = lane & 15;
  const int wr = wid >> 2, wc = wid & 3;
  const int sr0 = lane >> 2;

  const int bid = blockIdx.x;
  const int xcd = bid & 7, idx = bid >> 3;
  const int stl = idx >> 4, pos = idx & 15;
  const int m0 = (xcd * 4 + (pos >> 2)) * 256;
  const int n0 = (stl * 4 + (pos & 3)) * 256;

  f32x4 acc[8][4] = {};
  const int NT = Cdim / 32;

#define OSTAGE(buf_, t_) {                                                    \
    _Pragma("unroll") for (int j = 0; j < 2; ++j) {                           \
      const int rr = wid * 32 + j * 16 + sr0;                                 \
      const int sc = (lane & 3) ^ ((rr >> 1) & 3);                            \
      gl16(Yb + (size_t)(m0 + rr) * Cdim + (t_) * 32 + sc * 8,                \
           &sm.A[buf_][(wid * 32 + j * 16) * 32]);                            \
      gl16(Wt + (size_t)(n0 + rr) * Cdim + (t_) * 32 + sc * 8,                \
           &sm.B[buf_][(wid * 32 + j * 16) * 32]);                            \
    } }

  OSTAGE(0, 0)
  OSTAGE(1, 1)

  for (int t = 0; t < NT; ++t) {
    const int p = t & 1;
    if (t < NT - 1) asm volatile("s_waitcnt vmcnt(4)" ::: "memory");
    else            asm volatile("s_waitcnt vmcnt(0)" ::: "memory");
    __builtin_amdgcn_s_barrier();
    __builtin_amdgcn_sched_barrier(0);

    {
      bf16x8 a[8], b[4];
      const int ch = (g ^ ((l16 >> 1) & 3)) * 8;
      #pragma unroll
      for (int f = 0; f < 8; ++f)
        a[f] = *(const bf16x8*)&sm.A[p][(wr * 128 + f * 16 + l16) * 32 + ch];
      #pragma unroll
      for (int n = 0; n < 4; ++n)
        b[n] = *(const bf16x8*)&sm.B[p][(wc * 64 + n * 16 + l16) * 32 + ch];
      #pragma unroll
      for (int f = 0; f < 8; ++f)
        #pragma unroll
        for (int n = 0; n < 4; ++n)
          acc[f][n] = mfma16(a[f], b[n], acc[f][n]);
    }

    __builtin_amdgcn_sched_barrier(0);
    asm volatile("s_waitcnt lgkmcnt(0)" ::: "memory");
    __builtin_amdgcn_s_barrier();

    if (t + 2 < NT) OSTAGE(p, t + 2)
  }
#undef OSTAGE

  #pragma unroll
  for (int f = 0; f < 8; ++f)
    #pragma unroll
    for (int n = 0; n < 4; ++n)
      #pragma unroll
      for (int r = 0; r < 4; ++r)
        O[(size_t)(m0 + wr * 128 + f * 16 + g * 4 + r) * Cdim
          + (n0 + wc * 64 + n * 16 + l16)] = acc[f][n][r];
}

// ---- launch -----------------------------------------------------------------
extern "C" void kernel_launch(void* const* d_in, const int* in_sizes, int n_in,
                              void* d_out, int out_size, void* d_ws, size_t ws_size,
                              hipStream_t stream) {
  const float* x    = (const float*)d_in[0];
  const float* Wqkv = (const float*)d_in[1];
  const float* Wout = (const float*)d_in[2];
  float* out = (float*)d_out;

  float*  cosT   = (float*)d_ws;
  float*  sinT   = cosT + Tlen * 64;
  __bf16* Xb     = (__bf16*)(sinT + Tlen * 64);            // 32MB (reused as Y)
  __bf16* Wqkv_t = Xb + (size_t)Mrows * Cdim;              // 24MB [6144][2048]
  __bf16* Wout_t = Wqkv_t + (size_t)N_QKV * Cdim;          // 8MB  [2048][2048]
  __bf16* Qb     = Wout_t + (size_t)Cdim * Cdim;           // 32MB [B][H][T][D]
  __bf16* Kb     = Qb + (size_t)Bsz * Hn * Tlen * Dh;      // 32MB [B][H][T][D]
  __bf16* Vb     = Kb + (size_t)Bsz * Hn * Tlen * Dh;      // 32MB [B][H][D][T]
  __bf16* Yb     = Xb;

  rope_table_k<<<dim3(512), dim3(256), 0, stream>>>(cosT, sinT);
  f32_to_bf16_k<<<dim3(Mrows * Cdim / (256 * 8)), dim3(256), 0, stream>>>(x, Xb);
  transpose_to_bf16_k<<<dim3(N_QKV / 32, Cdim / 32), dim3(256), 0, stream>>>(
      Wqkv, Wqkv_t, Cdim, N_QKV);
  transpose_to_bf16_k<<<dim3(Cdim / 32, Cdim / 32), dim3(256), 0, stream>>>(
      Wout, Wout_t, Cdim, Cdim);
  qkv_gemm<<<dim3(768), dim3(512), 0, stream>>>(
      Xb, Wqkv_t, Qb, Kb, Vb, cosT, sinT);
  attn_fwd<<<dim3(Tlen / 64, Hn, Bsz), dim3(256), 0, stream>>>(Qb, Kb, Vb, Yb);
  out_gemm<<<dim3(256), dim3(512), 0, stream>>>(Yb, Wout_t, out);
}

// Round 16
// 665.299 us; speedup vs baseline: 2.8871x; 2.8871x over previous
//
#include <hip/hip_runtime.h>
#include <hip/hip_bf16.h>
#include <cmath>

// ---- constants -------------------------------------------------------------
#define Bsz   4
#define Tlen  2048
#define Cdim  2048
#define Hn    16
#define Dh    128
#define N_QKV 6144
#define Mrows 8192          // B*T

typedef __bf16 bf16x8 __attribute__((ext_vector_type(8)));
typedef __bf16 bf16x4 __attribute__((ext_vector_type(4)));
typedef float  f32x4  __attribute__((ext_vector_type(4)));
typedef uint32_t u32x2 __attribute__((ext_vector_type(2)));

__device__ __forceinline__ f32x4 mfma16(bf16x8 a, bf16x8 b, f32x4 c) {
  return __builtin_amdgcn_mfma_f32_16x16x32_bf16(a, b, c, 0, 0, 0);
}

__device__ __forceinline__ void gl16(const void* g, void* l) {
  __builtin_amdgcn_global_load_lds(
      (const __attribute__((address_space(1))) void*)g,
      (__attribute__((address_space(3))) void*)l, 16, 0, 0);
}

__device__ __forceinline__ uint32_t pack_bf16(float lo, float hi) {
  union { __bf16 h; unsigned short u; } a, b;
  a.h = (__bf16)lo; b.h = (__bf16)hi;
  return (uint32_t)a.u | ((uint32_t)b.u << 16);
}

// ---- 0) RoPE cos/sin table: [T][64] each ----------------------------------
__global__ void rope_table_k(float* __restrict__ cosT, float* __restrict__ sinT) {
  int idx = blockIdx.x * 256 + threadIdx.x;
  int t = idx >> 6, i = idx & 63;
  float invf = __expf(-(float)i * 0.14391156698f);   // 10000^(-i/64)
  float a = (float)t * invf;
  float s, c;
  sincosf(a, &s, &c);
  cosT[idx] = c;
  sinT[idx] = s;
}

// ---- 0b) X fp32 -> bf16 (row-major) ----------------------------------------
__global__ __launch_bounds__(256) void f32_to_bf16_k(
    const float* __restrict__ src, __bf16* __restrict__ dst) {
  size_t i = ((size_t)blockIdx.x * 256 + threadIdx.x) * 8;
  f32x4 a = *(const f32x4*)(src + i);
  f32x4 b = *(const f32x4*)(src + i + 4);
  bf16x8 o;
  o[0] = (__bf16)a[0]; o[1] = (__bf16)a[1]; o[2] = (__bf16)a[2]; o[3] = (__bf16)a[3];
  o[4] = (__bf16)b[0]; o[5] = (__bf16)b[1]; o[6] = (__bf16)b[2]; o[7] = (__bf16)b[3];
  *(bf16x8*)(dst + i) = o;
}

// ---- 0c) W fp32 [K][N] -> bf16 [N][K] (B^T form) ---------------------------
__global__ __launch_bounds__(256) void transpose_to_bf16_k(
    const float* __restrict__ src, __bf16* __restrict__ dst, int K, int N) {
  __shared__ float tile[32][33];
  int n0 = blockIdx.x * 32, k0 = blockIdx.y * 32;
  int tr = threadIdx.x >> 3, tc = (threadIdx.x & 7) * 4;
  f32x4 v = *(const f32x4*)&src[(size_t)(k0 + tr) * N + n0 + tc];
  tile[tr][tc + 0] = v[0]; tile[tr][tc + 1] = v[1];
  tile[tr][tc + 2] = v[2]; tile[tr][tc + 3] = v[3];
  __syncthreads();
  bf16x4 w;
  w[0] = (__bf16)tile[tc + 0][tr];
  w[1] = (__bf16)tile[tc + 1][tr];
  w[2] = (__bf16)tile[tc + 2][tr];
  w[3] = (__bf16)tile[tc + 3][tr];
  *(bf16x4*)&dst[(size_t)(n0 + tr) * K + k0 + tc] = w;
}

// ---- 1) QKV GEMM: 256x256, 8 waves, BK=64, counted-vmcnt dbuf --------------
// Xb [8192][2048] bf16, Wt [6144][2048] bf16 (B^T).
// Q,K RoPE'd -> [B][H][T][D]; V -> TRANSPOSED [B][H][D][T].
__global__ __launch_bounds__(512, 2) void qkv_gemm(
    const __bf16* __restrict__ Xb, const __bf16* __restrict__ Wt,
    __bf16* __restrict__ Qo, __bf16* __restrict__ Ko, __bf16* __restrict__ Vo,
    const float* __restrict__ cosT, const float* __restrict__ sinT)
{
  __shared__ union SM {
    struct { __bf16 A[2][256 * 64]; __bf16 B[2][256 * 64]; } s;  // 128 KB dbuf
    float C[64][265];                                            // epilogue
  } sm;

  const int tid = threadIdx.x, lane = tid & 63, wid = tid >> 6;
  const int g = lane >> 4, l16 = lane & 15;
  const int wr = wid >> 2, wc = wid & 3;       // 2 x 4 wave grid

  // supertile: 768 blocks = 8 xcd * 6 stl * 16 pos; each XCD owns 4 by-rows
  const int bid = blockIdx.x;
  const int xcd = bid & 7, idx = bid >> 3;
  const int stl = idx >> 4, pos = idx & 15;
  const int m0 = (xcd * 4 + (pos >> 2)) * 256;
  const int n0 = (stl * 4 + (pos & 3)) * 256;

  const int srow = tid >> 3;                   // 0..63
  const int schk = (tid & 7) ^ (srow & 7);
  const __bf16* gA = Xb + (size_t)(m0 + srow) * Cdim + schk * 8;
  const __bf16* gB = Wt + (size_t)(n0 + srow) * Cdim + schk * 8;
  const int ldst = wid * 512;

  f32x4 acc[8][4] = {};
  const int NT = Cdim / 64;   // 32 K-tiles

  #pragma unroll
  for (int r = 0; r < 4; ++r) {
    gl16(gA + (size_t)r * 64 * Cdim, &sm.s.A[0][r * 4096 + ldst]);
    gl16(gB + (size_t)r * 64 * Cdim, &sm.s.B[0][r * 4096 + ldst]);
  }
  #pragma unroll
  for (int r = 0; r < 4; ++r) {
    gl16(gA + 64 + (size_t)r * 64 * Cdim, &sm.s.A[1][r * 4096 + ldst]);
    gl16(gB + 64 + (size_t)r * 64 * Cdim, &sm.s.B[1][r * 4096 + ldst]);
  }

  for (int t = 0; t < NT; ++t) {
    const int p = t & 1;
    if (t < NT - 1) asm volatile("s_waitcnt vmcnt(8)" ::: "memory");
    else            asm volatile("s_waitcnt vmcnt(0)" ::: "memory");
    __builtin_amdgcn_s_barrier();
    __builtin_amdgcn_sched_barrier(0);

    #pragma unroll
    for (int kk = 0; kk < 2; ++kk) {
      bf16x8 a[8], b[4];
      const int ch = (((kk << 2) | g) ^ (l16 & 7)) * 8;
      #pragma unroll
      for (int f = 0; f < 8; ++f)
        a[f] = *(const bf16x8*)&sm.s.A[p][(wr * 128 + f * 16 + l16) * 64 + ch];
      #pragma unroll
      for (int n = 0; n < 4; ++n)
        b[n] = *(const bf16x8*)&sm.s.B[p][(wc * 64 + n * 16 + l16) * 64 + ch];
      #pragma unroll
      for (int f = 0; f < 8; ++f)
        #pragma unroll
        for (int n = 0; n < 4; ++n)
          acc[f][n] = mfma16(a[f], b[n], acc[f][n]);
    }

    __builtin_amdgcn_sched_barrier(0);
    asm volatile("s_waitcnt lgkmcnt(0)" ::: "memory");
    __builtin_amdgcn_s_barrier();

    if (t + 2 < NT) {
      const __bf16* pA = gA + (size_t)(t + 2) * 64;
      const __bf16* pB = gB + (size_t)(t + 2) * 64;
      #pragma unroll
      for (int r = 0; r < 4; ++r) {
        gl16(pA + (size_t)r * 64 * Cdim, &sm.s.A[p][r * 4096 + ldst]);
        gl16(pB + (size_t)r * 64 * Cdim, &sm.s.B[p][r * 4096 + ldst]);
      }
    }
  }

  // epilogue: four 64-row rounds through LDS f32
  const int sel = n0 >> 11;             // 0=q 1=k 2=v
  const int h0  = (n0 & 2047) >> 7;     // first of 2 heads in this tile
  const int erow = tid >> 3, q = tid & 7;
  const int dlo = (q & 3) * 16;
  const int clo = (q >> 2) * 128 + dlo;
  const int vcol = tid >> 1, vth = tid & 1;      // V^T path mapping

  #pragma unroll
  for (int rh = 0; rh < 4; ++rh) {
    if (wr == (rh >> 1)) {
      const int fb = (rh & 1) * 4;
      #pragma unroll
      for (int f2 = 0; f2 < 4; ++f2)
        #pragma unroll
        for (int n = 0; n < 4; ++n)
          #pragma unroll
          for (int r = 0; r < 4; ++r)
            sm.C[f2 * 16 + g * 4 + r][wc * 64 + n * 16 + l16] = acc[fb + f2][n][r];
    }
    __syncthreads();
    if (sel == 2) {
      // V^T write: thread owns (head', d) column, writes 32 t-contiguous vals
      const int hh = h0 + (vcol >> 7), d = vcol & 127;
      const int mb = m0 + rh * 64 + vth * 32;
      const int b_ = mb >> 11, tt = mb & 2047;
      __bf16* outp = Vo + (((size_t)(b_ * Hn + hh)) * Dh + d) * Tlen + tt;
      bf16x8 w[4];
      #pragma unroll
      for (int i = 0; i < 32; ++i)
        w[i >> 3][i & 7] = (__bf16)sm.C[vth * 32 + i][vcol];
      #pragma unroll
      for (int k = 0; k < 4; ++k) *(bf16x8*)&outp[k * 8] = w[k];
    } else {
      __bf16* dst = (sel == 0) ? Qo : Ko;
      const int m = m0 + rh * 64 + erow;
      const int b_ = m >> 11, t = m & 2047;
      __bf16* out = dst + (((size_t)(b_ * Hn + h0 + (q >> 2))) * Tlen + t) * Dh + dlo;
      const float* cb = cosT + t * 64 + dlo;
      const float* sb = sinT + t * 64 + dlo;
      bf16x8 o1[2], o2[2];
      #pragma unroll
      for (int i = 0; i < 16; ++i) {
        float v1 = sm.C[erow][clo + i];
        float v2 = sm.C[erow][clo + i + 64];
        float cs = cb[i], sn = sb[i];
        float r1 = v1 * cs - v2 * sn;
        float r2 = v2 * cs + v1 * sn;
        o1[i >> 3][i & 7] = (__bf16)r1;
        o2[i >> 3][i & 7] = (__bf16)r2;
      }
      *(bf16x8*)&out[0]  = o1[0];
      *(bf16x8*)&out[8]  = o1[1];
      *(bf16x8*)&out[64] = o2[0];
      *(bf16x8*)&out[72] = o2[1];
    }
    __syncthreads();
  }
}

// ---- 2) Flash attention (causal), swapped QK^T, in-register softmax --------
// Q,K bf16 [B][H][T][D]; V bf16 [B][H][D][T] (pre-transposed); Y -> [B][T][C].
__global__ __launch_bounds__(256, 2) void attn_fwd(
    const __bf16* __restrict__ Qg, const __bf16* __restrict__ Kg,
    const __bf16* __restrict__ Vtg, __bf16* __restrict__ Yg)
{
  __shared__ __bf16 Ks[2][64 * 128];       // XOR-chunk swizzled
  __shared__ __bf16 Vt[2][128 * 64];       // V^T tile, swizzled
  __shared__ uint32_t Ps2[4][16 * 34 + 2]; // per-wave P in B-frag layout (u32 pairs)

  const int tid = threadIdx.x, lane = tid & 63, wid = tid >> 6;
  const int g = lane >> 4, l16 = lane & 15;
  const int qt = gridDim.x - 1 - blockIdx.x;     // heavy blocks first
  const int q0 = qt * 64;
  const size_t bh = (size_t)blockIdx.z * Hn + blockIdx.y;
  const __bf16* Kbase = Kg + bh * ((size_t)Tlen * Dh);
  const __bf16* Vbase = Vtg + bh * ((size_t)Dh * Tlen);

  const int q_glob = q0 + wid * 16 + l16;        // this lane's q row

  // Q fragments in registers: B-operand, B[k=8g+j][col=q=l16]
  bf16x8 aq[4];
  {
    const __bf16* qrow = Qg + (bh * Tlen + q_glob) * Dh;
    #pragma unroll
    for (int ks = 0; ks < 4; ++ks)
      aq[ks] = *(const bf16x8*)(qrow + ks * 32 + 8 * g);
  }

  float m_r = -1e30f, l_r = 0.f;
  f32x4 o[8] = {};                               // O^T: d = 16n2+4g+r, q = l16
  const float k_e = 0.08838834764831845f * 1.4426950408889634f; // scl*log2(e)

  const int NKV = qt + 1;

  const int krow = lane >> 4, kchk = lane & 15;
  const int vrow = lane >> 3, vchk = lane & 7;

#define STAGE_KV(kv0_, buf_)                                                    \
  {                                                                             \
    _Pragma("unroll")                                                           \
    for (int rr = 0; rr < 4; ++rr) {                                            \
      const int row = wid * 16 + rr * 4 + krow;                                 \
      const int sc = kchk ^ (row & 7);                                          \
      gl16(Kbase + (size_t)((kv0_) + row) * Dh + sc * 8,                        \
           &Ks[buf_][(wid * 16 + rr * 4) * 128]);                               \
    }                                                                           \
    _Pragma("unroll")                                                           \
    for (int rr = 0; rr < 4; ++rr) {                                            \
      const int row = wid * 32 + rr * 8 + vrow;                                 \
      const int sc = vchk ^ (row & 7);                                          \
      gl16(Vbase + (size_t)row * Tlen + (kv0_) + sc * 8,                        \
           &Vt[buf_][(wid * 32 + rr * 8) * 64]);                                \
    }                                                                           \
  }

  STAGE_KV(0, 0);

  for (int it = 0; it < NKV; ++it) {
    const int p = it & 1;
    if (it + 1 < NKV) {
      STAGE_KV((it + 1) * 64, (it + 1) & 1);
      asm volatile("s_waitcnt vmcnt(8)" ::: "memory");
    } else {
      asm volatile("s_waitcnt vmcnt(0)" ::: "memory");
    }
    __builtin_amdgcn_s_barrier();
    __builtin_amdgcn_sched_barrier(0);

    // S^T = K Q^T : s[nf][r] = S[kv = it*64 + nf*16 + 4g + r][q = l16]
    f32x4 s[4] = {};
    __builtin_amdgcn_s_setprio(1);
    #pragma unroll
    for (int ks = 0; ks < 4; ++ks) {
      const int ch = ((4 * ks + g) ^ (l16 & 7)) * 8;
      #pragma unroll
      for (int nf = 0; nf < 4; ++nf) {
        bf16x8 bk = *(const bf16x8*)&Ks[p][(nf * 16 + l16) * 128 + ch];
        s[nf] = mfma16(bk, aq[ks], s[nf]);     // swapped: A=K, B=Q^T
      }
    }
    __builtin_amdgcn_s_setprio(0);

    if (it == qt) {                              // diagonal tile: causal mask
      const int kvb = it * 64 + 4 * g;
      #pragma unroll
      for (int nf = 0; nf < 4; ++nf)
        #pragma unroll
        for (int r = 0; r < 4; ++r)
          if (kvb + nf * 16 + r > q_glob) s[nf][r] = -1e30f;
    }

    // per-lane max over 16 kv values + 2-stage cross-g reduce
    float mx = s[0][0];
    #pragma unroll
    for (int nf = 0; nf < 4; ++nf)
      #pragma unroll
      for (int r = 0; r < 4; ++r) mx = fmaxf(mx, s[nf][r]);
    mx = fmaxf(mx, __shfl_xor(mx, 16, 64));
    mx = fmaxf(mx, __shfl_xor(mx, 32, 64));

    // T13 defer-max: only rescale when max grew by more than THR=8.
    // Exact math: P bounded by e^8, normalizer shift cancels in o/l.
    if (!__all(mx - m_r <= 8.0f)) {
      const float mn = fmaxf(m_r, mx);
      const float al = exp2f((m_r - mn) * k_e);
      m_r = mn;
      l_r *= al;
      #pragma unroll
      for (int n2 = 0; n2 < 8; ++n2)
        #pragma unroll
        for (int r = 0; r < 4; ++r) o[n2][r] *= al;
    }

    const float mk = -m_r * k_e;
    float rs = 0.f;
    #pragma unroll
    for (int nf = 0; nf < 4; ++nf)
      #pragma unroll
      for (int r = 0; r < 4; ++r) {
        const float pv = exp2f(fmaf(s[nf][r], k_e, mk));
        s[nf][r] = pv;
        rs += pv;
      }
    rs += __shfl_xor(rs, 16, 64);
    rs += __shfl_xor(rs, 32, 64);
    l_r += rs;

    // P -> B-fragment layout via per-wave LDS: row q=l16, u32 col = kv/2
    #pragma unroll
    for (int nf = 0; nf < 4; ++nf) {
      u32x2 wv;
      wv.x = pack_bf16(s[nf][0], s[nf][1]);
      wv.y = pack_bf16(s[nf][2], s[nf][3]);
      *(u32x2*)&Ps2[wid][l16 * 34 + nf * 8 + 2 * g] = wv;   // kv = 16nf+4g+0..3
    }
    asm volatile("s_waitcnt lgkmcnt(0)" ::: "memory");
    __builtin_amdgcn_sched_barrier(0);

    union { u32x2 h[2]; bf16x8 v; } pb0, pb1;
    pb0.h[0] = *(const u32x2*)&Ps2[wid][l16 * 34 + 4 * g];
    pb0.h[1] = *(const u32x2*)&Ps2[wid][l16 * 34 + 4 * g + 2];
    pb1.h[0] = *(const u32x2*)&Ps2[wid][l16 * 34 + 16 + 4 * g];
    pb1.h[1] = *(const u32x2*)&Ps2[wid][l16 * 34 + 16 + 4 * g + 2];

    const int c0 = (g ^ (l16 & 7)) * 8;
    const int c1 = ((4 + g) ^ (l16 & 7)) * 8;
    __builtin_amdgcn_s_setprio(1);
    #pragma unroll
    for (int n2 = 0; n2 < 8; ++n2) {
      bf16x8 vb0 = *(const bf16x8*)&Vt[p][(n2 * 16 + l16) * 64 + c0];
      bf16x8 vb1 = *(const bf16x8*)&Vt[p][(n2 * 16 + l16) * 64 + c1];
      o[n2] = mfma16(vb0, pb0.v, o[n2]);         // O^T = V^T P
      o[n2] = mfma16(vb1, pb1.v, o[n2]);
    }
    __builtin_amdgcn_s_setprio(0);

    asm volatile("s_waitcnt lgkmcnt(0)" ::: "memory");
    __builtin_amdgcn_sched_barrier(0);
    __builtin_amdgcn_s_barrier();
  }
#undef STAGE_KV

  const float inv = 1.0f / l_r;
  // lane writes q-row q_glob, d = 16n2 + 4g + r (bf16x4 8B stores)
  __bf16* yrow = Yg + ((size_t)(blockIdx.z * Tlen + q0 + wid * 16 + l16)) * Cdim
               + blockIdx.y * Dh;
  #pragma unroll
  for (int n2 = 0; n2 < 8; ++n2) {
    bf16x4 w;
    #pragma unroll
    for (int r = 0; r < 4; ++r) w[r] = (__bf16)(o[n2][r] * inv);
    *(bf16x4*)&yrow[n2 * 16 + 4 * g] = w;
  }
}

// ---- 3) output GEMM: 256x256, 8 waves, BK=64, counted-vmcnt dbuf -----------
__global__ __launch_bounds__(512, 2) void out_gemm(
    const __bf16* __restrict__ Yb, const __bf16* __restrict__ Wt,
    float* __restrict__ O)
{
  __shared__ struct { __bf16 A[2][256 * 64]; __bf16 B[2][256 * 64]; } sm;

  const int tid = threadIdx.x, lane = tid & 63, wid = tid >> 6;
  const int g = lane >> 4, l16 = lane & 15;
  const int wr = wid >> 2, wc = wid & 3;

  const int bid = blockIdx.x;
  const int xcd = bid & 7, idx = bid >> 3;
  const int stl = idx >> 4, pos = idx & 15;
  const int m0 = (xcd * 4 + (pos >> 2)) * 256;
  const int n0 = (stl * 4 + (pos & 3)) * 256;

  const int srow = tid >> 3;
  const int schk = (tid & 7) ^ (srow & 7);
  const __bf16* gA = Yb + (size_t)(m0 + srow) * Cdim + schk * 8;
  const __bf16* gB = Wt + (size_t)(n0 + srow) * Cdim + schk * 8;
  const int ldst = wid * 512;

  f32x4 acc[8][4] = {};
  const int NT = Cdim / 64;

  #pragma unroll
  for (int r = 0; r < 4; ++r) {
    gl16(gA + (size_t)r * 64 * Cdim, &sm.A[0][r * 4096 + ldst]);
    gl16(gB + (size_t)r * 64 * Cdim, &sm.B[0][r * 4096 + ldst]);
  }
  #pragma unroll
  for (int r = 0; r < 4; ++r) {
    gl16(gA + 64 + (size_t)r * 64 * Cdim, &sm.A[1][r * 4096 + ldst]);
    gl16(gB + 64 + (size_t)r * 64 * Cdim, &sm.B[1][r * 4096 + ldst]);
  }

  for (int t = 0; t < NT; ++t) {
    const int p = t & 1;
    if (t < NT - 1) asm volatile("s_waitcnt vmcnt(8)" ::: "memory");
    else            asm volatile("s_waitcnt vmcnt(0)" ::: "memory");
    __builtin_amdgcn_s_barrier();
    __builtin_amdgcn_sched_barrier(0);

    #pragma unroll
    for (int kk = 0; kk < 2; ++kk) {
      bf16x8 a[8], b[4];
      const int ch = (((kk << 2) | g) ^ (l16 & 7)) * 8;
      #pragma unroll
      for (int f = 0; f < 8; ++f)
        a[f] = *(const bf16x8*)&sm.A[p][(wr * 128 + f * 16 + l16) * 64 + ch];
      #pragma unroll
      for (int n = 0; n < 4; ++n)
        b[n] = *(const bf16x8*)&sm.B[p][(wc * 64 + n * 16 + l16) * 64 + ch];
      #pragma unroll
      for (int f = 0; f < 8; ++f)
        #pragma unroll
        for (int n = 0; n < 4; ++n)
          acc[f][n] = mfma16(a[f], b[n], acc[f][n]);
    }

    __builtin_amdgcn_sched_barrier(0);
    asm volatile("s_waitcnt lgkmcnt(0)" ::: "memory");
    __builtin_amdgcn_s_barrier();

    if (t + 2 < NT) {
      const __bf16* pA = gA + (size_t)(t + 2) * 64;
      const __bf16* pB = gB + (size_t)(t + 2) * 64;
      #pragma unroll
      for (int r = 0; r < 4; ++r) {
        gl16(pA + (size_t)r * 64 * Cdim, &sm.A[p][r * 4096 + ldst]);
        gl16(pB + (size_t)r * 64 * Cdim, &sm.B[p][r * 4096 + ldst]);
      }
    }
  }

  #pragma unroll
  for (int f = 0; f < 8; ++f)
    #pragma unroll
    for (int n = 0; n < 4; ++n)
      #pragma unroll
      for (int r = 0; r < 4; ++r)
        O[(size_t)(m0 + wr * 128 + f * 16 + g * 4 + r) * Cdim
          + (n0 + wc * 64 + n * 16 + l16)] = acc[f][n][r];
}

// ---- launch -----------------------------------------------------------------
extern "C" void kernel_launch(void* const* d_in, const int* in_sizes, int n_in,
                              void* d_out, int out_size, void* d_ws, size_t ws_size,
                              hipStream_t stream) {
  const float* x    = (const float*)d_in[0];
  const float* Wqkv = (const float*)d_in[1];
  const float* Wout = (const float*)d_in[2];
  float* out = (float*)d_out;

  float*  cosT   = (float*)d_ws;
  float*  sinT   = cosT + Tlen * 64;
  __bf16* Xb     = (__bf16*)(sinT + Tlen * 64);            // 32MB (reused as Y)
  __bf16* Wqkv_t = Xb + (size_t)Mrows * Cdim;              // 24MB [6144][2048]
  __bf16* Wout_t = Wqkv_t + (size_t)N_QKV * Cdim;          // 8MB  [2048][2048]
  __bf16* Qb     = Wout_t + (size_t)Cdim * Cdim;           // 32MB [B][H][T][D]
  __bf16* Kb     = Qb + (size_t)Bsz * Hn * Tlen * Dh;      // 32MB [B][H][T][D]
  __bf16* Vb     = Kb + (size_t)Bsz * Hn * Tlen * Dh;      // 32MB [B][H][D][T]
  __bf16* Yb     = Xb;

  rope_table_k<<<dim3(512), dim3(256), 0, stream>>>(cosT, sinT);
  f32_to_bf16_k<<<dim3(Mrows * Cdim / (256 * 8)), dim3(256), 0, stream>>>(x, Xb);
  transpose_to_bf16_k<<<dim3(N_QKV / 32, Cdim / 32), dim3(256), 0, stream>>>(
      Wqkv, Wqkv_t, Cdim, N_QKV);
  transpose_to_bf16_k<<<dim3(Cdim / 32, Cdim / 32), dim3(256), 0, stream>>>(
      Wout, Wout_t, Cdim, Cdim);
  qkv_gemm<<<dim3(768), dim3(512), 0, stream>>>(
      Xb, Wqkv_t, Qb, Kb, Vb, cosT, sinT);
  attn_fwd<<<dim3(Tlen / 64, Hn, Bsz), dim3(256), 0, stream>>>(Qb, Kb, Vb, Yb);
  out_gemm<<<dim3(256), dim3(512), 0, stream>>>(Yb, Wout_t, out);
}